// Round 3
// baseline (191.612 us; speedup 1.0000x reference)
//
#include <hip/hip_runtime.h>
#include <hip/hip_fp16.h>
#include <math.h>

// ---------------- problem constants ----------------
#define NB    256
#define NTOKP 197
#define NTOK  196
#define NC    768
#define NHID  192
#define NH    14
#define NVF   8        // rfft cols = 14/2+1
#define CHT   64       // channels per tile
#define NTILE 12       // 768/64

// twiddles (compile-time folded under full unroll)
constexpr float CT14[14] = {
    1.0f, 0.9009688679024191f, 0.6234898018587336f, 0.22252093395631445f,
    -0.22252093395631434f, -0.6234898018587335f, -0.9009688679024191f, -1.0f,
    -0.9009688679024191f, -0.6234898018587335f, -0.22252093395631434f,
    0.22252093395631445f, 0.6234898018587336f, 0.9009688679024191f};
constexpr float ST14[14] = {
    0.0f, 0.4338837391175581f, 0.7818314824680298f, 0.9749279121818236f,
    0.9749279121818236f, 0.7818314824680299f, 0.43388373911755823f, 0.0f,
    -0.43388373911755823f, -0.7818314824680299f, -0.9749279121818236f,
    -0.9749279121818236f, -0.7818314824680298f, -0.4338837391175581f};
constexpr float C7[7] = {1.0f, 0.6234898018587336f, -0.22252093395631434f,
                         -0.9009688679024191f, -0.9009688679024191f,
                         -0.22252093395631434f, 0.6234898018587336f};
constexpr float S7[7] = {0.0f, 0.7818314824680298f, 0.9749279121818236f,
                         0.4338837391175581f, -0.4338837391175581f,
                         -0.9749279121818236f, -0.7818314824680298f};

__device__ __forceinline__ unsigned int pack_h2(float a, float b) {
  __half2 h = __floats2half2_rn(a, b);
  return *(unsigned int*)&h;
}
__device__ __forceinline__ float2 unpack_h2(unsigned int p) {
  __half2 h = *(__half2*)&p;
  return __half22float2(h);
}

// ---------------- K1: LayerNorm stats per (b, token) -> float2(mean, rstd) ----
__global__ __launch_bounds__(256) void k_stats(const float* __restrict__ x,
                                               float2* __restrict__ msv) {
  int row = blockIdx.x * 4 + (threadIdx.x >> 6);
  int lane = threadIdx.x & 63;
  if (row >= NB * NTOK) return;
  int b = row / NTOK, t = row - b * NTOK;
  const float4* p = (const float4*)(x + ((size_t)b * NTOKP + 1 + t) * NC);
  float s = 0.f, ss = 0.f;
#pragma unroll
  for (int k = 0; k < 3; ++k) {
    float4 v = p[lane + k * 64];
    s += v.x + v.y + v.z + v.w;
    ss += v.x * v.x + v.y * v.y + v.z * v.z + v.w * v.w;
  }
#pragma unroll
  for (int off = 32; off; off >>= 1) {
    s += __shfl_down(s, off);
    ss += __shfl_down(ss, off);
  }
  if (lane == 0) {
    float m = s * (1.f / NC);
    float var = ss * (1.f / NC) - m * m;
    msv[row] = make_float2(m, rsqrtf(var + 1e-5f));
  }
}

// ---------------- K2: forward DFT + energy ----------------
__global__ __launch_bounds__(256) void k_fwd(const float* __restrict__ x,
                                             const float* __restrict__ gamma,
                                             const float* __restrict__ beta,
                                             const float2* __restrict__ msv,
                                             float* __restrict__ energy) {
  __shared__ unsigned int A[NH * NVF * CHT];  // [i][v][c] packed fp16 (re,im) 28.7KB
  __shared__ float2 ms[NTOK];
  __shared__ float esum[256];
  int b = blockIdx.y, c0 = blockIdx.x * CHT, tid = threadIdx.x;
  int c = tid & 63, w = tid >> 6;

  for (int k = tid; k < NTOK; k += 256) ms[k] = msv[b * NTOK + k];
  float g = gamma[c0 + c], be = beta[c0 + c];
  __syncthreads();

  // stage A: per (c,i): A[i,v] = sum_j xn[i,j] e^{-2pi i v j/14}
#pragma unroll 1
  for (int i = w; i < NH; i += 4) {
    const float* xr = x + ((size_t)b * NTOKP + 1 + i * NH) * NC + c0 + c;
    float xn_[NH];
#pragma unroll
    for (int j = 0; j < NH; ++j) {
      float2 m = ms[i * NH + j];
      xn_[j] = (xr[(size_t)j * NC] - m.x) * m.y * g + be;
    }
    float ar[NVF] = {}, ai[NVF] = {};
#pragma unroll
    for (int j = 0; j < NH; ++j) {
#pragma unroll
      for (int v = 0; v < NVF; ++v) {
        ar[v] = fmaf(xn_[j], CT14[(v * j) % 14], ar[v]);
        ai[v] = fmaf(-xn_[j], ST14[(v * j) % 14], ai[v]);
      }
    }
#pragma unroll
    for (int v = 0; v < NVF; ++v) A[(i * NVF + v) * CHT + c] = pack_h2(ar[v], ai[v]);
  }
  __syncthreads();

  // stage B (radix-2 over rows): per (c, v in {2w,2w+1})
  float part = 0.f;
#pragma unroll 1
  for (int vv = 0; vv < 2; ++vv) {
    int v = w * 2 + vv;
    const unsigned int* Ac = A + v * CHT + c;
    float er[7], ei[7], orr[7], oii[7];
#pragma unroll
    for (int k = 0; k < 7; ++k) { er[k] = 0.f; ei[k] = 0.f; orr[k] = 0.f; oii[k] = 0.f; }
#pragma unroll
    for (int m = 0; m < 7; ++m) {
      float2 ae = unpack_h2(Ac[(2 * m) * NVF * CHT]);
      float2 ao = unpack_h2(Ac[(2 * m + 1) * NVF * CHT]);
#pragma unroll
      for (int k = 0; k < 7; ++k) {
        int t = (k * m) % 7;
        er[k] = fmaf(ae.x, C7[t], fmaf(ae.y, S7[t], er[k]));
        ei[k] = fmaf(ae.y, C7[t], fmaf(-ae.x, S7[t], ei[k]));
        orr[k] = fmaf(ao.x, C7[t], fmaf(ao.y, S7[t], orr[k]));
        oii[k] = fmaf(ao.y, C7[t], fmaf(-ao.x, S7[t], oii[k]));
      }
    }
#pragma unroll
    for (int u = 0; u < NH; ++u) {
      int k = u % 7;
      float tr = fmaf(orr[k], CT14[u], oii[k] * ST14[u]);
      float ti = fmaf(oii[k], CT14[u], -orr[k] * ST14[u]);
      float sr = er[k] + tr, si = ei[k] + ti;
      float m2 = fmaf(sr, sr, si * si);
      float lg = __logf(1.f + __builtin_amdgcn_sqrtf(m2) * (1.f / 14.f));
      if (u == 0) {
        if (v != 0) part += lg;  // DC bin (u=0,v=0) excluded (zero-mean input)
      } else {
        part += lg;
      }
    }
  }
  esum[tid] = part;
  __syncthreads();
  if (w == 0) {
    float e = esum[c] + esum[c + 64] + esum[c + 128] + esum[c + 192];
    energy[b * NC + c0 + c] = e * (1.f / 112.f);
  }
}

// ---------------- K3: per-batch MLP -> m2s = 2*mu^2*sigma + eps ----------------
__global__ __launch_bounds__(256) void k_mlp(const float* __restrict__ energy,
                                             const float* __restrict__ w1,
                                             const float* __restrict__ b1,
                                             const float* __restrict__ w2,
                                             const float* __restrict__ b2,
                                             float* __restrict__ m2s) {
  __shared__ float e[NC];
  __shared__ float hd[NHID];
  int b = blockIdx.x, tid = threadIdx.x;
  for (int k = tid; k < NC; k += 256) e[k] = energy[b * NC + k];
  __syncthreads();
  if (tid < NHID) {
    float acc = b1[tid];
#pragma unroll 4
    for (int cc = 0; cc < NC; ++cc) acc = fmaf(e[cc], w1[cc * NHID + tid], acc);
    hd[tid] = 0.5f * acc * (1.f + erff(acc * 0.70710678118654752f));  // exact gelu
  }
  __syncthreads();
  if (tid < 64) {
    float p0 = 0.f, p1 = 0.f;
#pragma unroll
    for (int k = 0; k < 3; ++k) {
      float hv = hd[tid + k * 64];
      p0 = fmaf(hv, w2[2 * (tid + k * 64)], p0);
      p1 = fmaf(hv, w2[2 * (tid + k * 64) + 1], p1);
    }
#pragma unroll
    for (int off = 32; off; off >>= 1) {
      p0 += __shfl_down(p0, off);
      p1 += __shfl_down(p1, off);
    }
    if (tid == 0) {
      float o0 = p0 + b2[0], o1 = p1 + b2[1];
      float muv = 9.899494936611665f / (1.f + expf(-o0));
      muv = fmaxf(muv, 1.f);
      float sp = (o1 > 20.f) ? o1 : log1pf(expf(o1));
      float sg = fmaxf(sp, 0.1f);
      m2s[b] = 2.f * muv * muv * sg + 1e-6f;
    }
  }
}

// ---------------- K4: separable circulant filter + residual ----------------
// filtered = K (x) K (x) xn  (mean path drops out: mask[0,0]=1 => K*const=const)
// stage2 reconstructs xv from the fp16 xn tile: xv=(xn-beta)/(gamma*rstd)+mu
__global__ __launch_bounds__(256) void k_inv(const float* __restrict__ x,
                                             const float* __restrict__ gamma,
                                             const float* __restrict__ beta,
                                             const float2* __restrict__ msv,
                                             const float* __restrict__ m2s,
                                             const float* __restrict__ rscale,
                                             float* __restrict__ out) {
  __shared__ unsigned int X[NH * 7 * CHT];  // xn fp16 pairs  25KB
  __shared__ unsigned int T[NH * 7 * CHT];  // y  fp16 pairs  25KB
  __shared__ float2 ms[NTOK];               // (mean, rstd)
  __shared__ float rr[NTOK];                // 1/rstd
  __shared__ float wexp[NH];
  __shared__ float kc[NH];
  int b = blockIdx.y, c0 = blockIdx.x * CHT, tid = threadIdx.x;
  int c = tid & 63, w = tid >> 6;
  float rs = rscale[0];

  for (int k = tid; k < NTOK; k += 256) {
    float2 m = msv[b * NTOK + k];
    ms[k] = m;
    rr[k] = 1.f / m.y;
  }
  if (tid < CHT) {  // cls-token passthrough
    size_t idx = (size_t)b * NTOKP * NC + c0 + tid;
    out[idx] = x[idx];
  }
  float msb = m2s[b];
  if (tid < NH) {
    int f = (tid <= 7) ? tid : 14 - tid;
    wexp[tid] = __expf(-(float)(f * f) / msb);
  }
  __syncthreads();
  if (tid < NH) {
    float s = 0.f;
#pragma unroll
    for (int k = 0; k < NH; ++k) s = fmaf(wexp[k], CT14[(k * tid) % 14], s);
    kc[tid] = s * (1.f / 14.f);
  }
  float g = gamma[c0 + c], be = beta[c0 + c];
  float rg = 1.f / g;
  __syncthreads();

  float kr[NH];
#pragma unroll
  for (int d = 0; d < NH; ++d) kr[d] = kc[d];

  // stage 1: per (c,i): xn row -> LDS; y[i,j'] = sum_j xn[i,j]*kc[(j'-j)%14] -> LDS
#pragma unroll 1
  for (int i = w; i < NH; i += 4) {
    const float* xr = x + ((size_t)b * NTOKP + 1 + i * NH) * NC + c0 + c;
    float xn_[NH];
#pragma unroll
    for (int j = 0; j < NH; ++j) {
      float2 m = ms[i * NH + j];
      xn_[j] = (xr[(size_t)j * NC] - m.x) * m.y * g + be;
    }
#pragma unroll
    for (int k = 0; k < 7; ++k)
      X[(i * 7 + k) * CHT + c] = pack_h2(xn_[2 * k], xn_[2 * k + 1]);
#pragma unroll
    for (int jp = 0; jp < 7; ++jp) {
      float y0 = 0.f, y1 = 0.f;
#pragma unroll
      for (int j = 0; j < NH; ++j) {
        y0 = fmaf(xn_[j], kr[(2 * jp - j + 28) % 14], y0);
        y1 = fmaf(xn_[j], kr[(2 * jp + 1 - j + 28) % 14], y1);
      }
      T[(i * 7 + jp) * CHT + c] = pack_h2(y0, y1);
    }
  }
  __syncthreads();

  // stage 2: per (c,jq): z[i'] = sum_i y[i,jq]*kc[(i'-i)%14]; out = xv + rs*(z-xn)
#pragma unroll 1
  for (int jq = w; jq < NH; jq += 4) {
    int jp = jq >> 1, hi = jq & 1;
    float y[NH];
#pragma unroll
    for (int i = 0; i < NH; ++i) {
      float2 v = unpack_h2(T[(i * 7 + jp) * CHT + c]);
      y[i] = hi ? v.y : v.x;
    }
    float* outr = out + ((size_t)b * NTOKP + 1 + jq) * NC + c0 + c;
#pragma unroll
    for (int ii = 0; ii < NH; ++ii) {
      float z = 0.f;
#pragma unroll
      for (int i = 0; i < NH; ++i) z = fmaf(y[i], kr[(ii - i + 28) % 14], z);
      float2 v = unpack_h2(X[(ii * 7 + jp) * CHT + c]);
      float xnv = hi ? v.y : v.x;
      int t = ii * NH + jq;
      float xv = fmaf((xnv - be) * rg, rr[t], ms[t].x);
      outr[(size_t)ii * NH * NC] = xv + rs * (z - xnv);
    }
  }
}

extern "C" void kernel_launch(void* const* d_in, const int* in_sizes, int n_in,
                              void* d_out, int out_size, void* d_ws, size_t ws_size,
                              hipStream_t stream) {
  (void)in_sizes; (void)n_in; (void)out_size; (void)ws_size;
  const float* x      = (const float*)d_in[0];
  const float* gamma  = (const float*)d_in[1];
  const float* beta   = (const float*)d_in[2];
  const float* w1     = (const float*)d_in[3];
  const float* b1     = (const float*)d_in[4];
  const float* w2     = (const float*)d_in[5];
  const float* b2     = (const float*)d_in[6];
  const float* rscale = (const float*)d_in[7];
  float* out = (float*)d_out;

  float* wsf    = (float*)d_ws;
  float2* msv   = (float2*)wsf;        // 50176 float2
  float* energy = wsf + 100352;        // 196608
  float* m2s    = wsf + 296960;        // 256  (total ~1.2 MB)

  k_stats<<<(NB * NTOK + 3) / 4, 256, 0, stream>>>(x, msv);
  k_fwd<<<dim3(NTILE, NB), 256, 0, stream>>>(x, gamma, beta, msv, energy);
  k_mlp<<<NB, 256, 0, stream>>>(energy, w1, b1, w2, b2, m2s);
  k_inv<<<dim3(NTILE, NB), 256, 0, stream>>>(x, gamma, beta, msv, m2s, rscale,
                                             out);
}